// Round 1
// baseline (82.249 us; speedup 1.0000x reference)
//
#include <hip/hip_runtime.h>

#define T_FRAMES 75
#define C_CH 3
#define HW4 (112 * 112 / 4)   // 3136 float4 per frame-slab
#define P_DEL 0.05f

// One thread per batch: replay the scan on indices only.
// src_map[b][j] = input frame index that output slot j holds.
__global__ void jitter_map_kernel(const float* __restrict__ u,
                                  int* __restrict__ src_map, int B) {
    int b = blockIdx.x * blockDim.x + threadIdx.x;
    if (b >= B) return;
    const float* ub = u + b * T_FRAMES;
    int src[T_FRAMES];
    int del[T_FRAMES];
    for (int t = 0; t < T_FRAMES; ++t) {
        src[t] = t;                       // out starts as a copy of input
        del[t] = (ub[t] < P_DEL) ? 1 : 0; // prob_del
    }
    int cnt = 0;
    for (int t = 0; t < T_FRAMES; ++t) {
        // step 1: keep frame t if not deleted
        if (!del[t] && cnt < T_FRAMES) {
            src[cnt] = t;
            ++cnt;
        }
        // step 2: duplicate from INPUT index (cnt-1) if reversed del-mask fires
        if (del[T_FRAMES - 1 - t] && cnt > 0 && cnt < T_FRAMES) {
            src[cnt] = cnt - 1;           // reads from input, per reference
            ++cnt;
        }
    }
    int* sm = src_map + b * T_FRAMES;
    for (int t = 0; t < T_FRAMES; ++t) sm[t] = src[t];
}

// One block per (b, c, j) slab: coalesced float4 copy of one 112x112 frame.
__global__ void jitter_gather_kernel(const float4* __restrict__ x,
                                     float4* __restrict__ out,
                                     const int* __restrict__ src_map) {
    int slab = blockIdx.x;                       // [0, B*C*T)
    int b   = slab / (C_CH * T_FRAMES);
    int rem = slab % (C_CH * T_FRAMES);
    int c   = rem / T_FRAMES;
    int j   = rem % T_FRAMES;
    int s = src_map[b * T_FRAMES + j];           // wave-uniform scalar load
    const float4* srcp = x + ((size_t)(b * C_CH + c) * T_FRAMES + s) * HW4;
    float4*       dstp = out + (size_t)slab * HW4;
    for (int i = threadIdx.x; i < HW4; i += blockDim.x)
        dstp[i] = srcp[i];
}

extern "C" void kernel_launch(void* const* d_in, const int* in_sizes, int n_in,
                              void* d_out, int out_size, void* d_ws, size_t ws_size,
                              hipStream_t stream) {
    const float* x = (const float*)d_in[0];       // [B, C, T, H, W] fp32
    const float* u = (const float*)d_in[1];       // [B, T] fp32
    float* out = (float*)d_out;
    int* src_map = (int*)d_ws;                    // B*T ints = 4.8 KB

    int B = in_sizes[1] / T_FRAMES;               // 16

    jitter_map_kernel<<<1, 64, 0, stream>>>(u, src_map, B);

    int slabs = B * C_CH * T_FRAMES;              // 3600
    jitter_gather_kernel<<<slabs, 256, 0, stream>>>(
        (const float4*)x, (float4*)out, src_map);
}